// Round 1
// baseline (174.494 us; speedup 1.0000x reference)
//
#include <hip/hip_runtime.h>

// SiamNet_D: tracking IOU loss.
// Key insight: softmax over 2 logits is monotone in (l1-l0), and the final
// loss only reads the argmax anchor per batch -> locs (102MB) needs only 4
// gathered floats/batch; only clss (51.2MB) must be fully scanned.

#define NANCH 3125   // 5*25*25
#define NB    2048

__global__ __launch_bounds__(256) void siam_argmax_iou(
    const float* __restrict__ bboxs,
    const float* __restrict__ bboxs_prev,
    const float* __restrict__ clss,
    const float* __restrict__ locs,
    const float* __restrict__ anchors,
    const float* __restrict__ LR,
    float* __restrict__ ws_iou)
{
    const int b   = blockIdx.x;
    const int tid = threadIdx.x;

    // Two contiguous logit segments for this batch:
    //   l0(a) = clss[b*6250 + a], l1(a) = clss[b*6250 + 3125 + a]
    const float* c0 = clss + (size_t)b * (2 * NANCH);
    const float* c1 = c0 + NANCH;

    // Per-thread argmax of d = l1 - l0 (monotone proxy for the 2-way softmax).
    // Ascending-a scan + strict '>' keeps the first-index tie-break.
    float bestd = -3.402823466e+38f;
    int   besta = 0;
    for (int a = tid; a < NANCH; a += 256) {
        float d = c1[a] - c0[a];
        if (d > bestd) { bestd = d; besta = a; }
    }

    // Wave(64)-level reduce, tie-break toward smaller anchor index.
    #pragma unroll
    for (int off = 32; off > 0; off >>= 1) {
        float od = __shfl_down(bestd, off, 64);
        int   oa = __shfl_down(besta, off, 64);
        if (od > bestd || (od == bestd && oa < besta)) { bestd = od; besta = oa; }
    }

    __shared__ float sd[4];
    __shared__ int   sa[4];
    const int wid = tid >> 6;
    if ((tid & 63) == 0) { sd[wid] = bestd; sa[wid] = besta; }
    __syncthreads();

    if (tid == 0) {
        bestd = sd[0]; besta = sa[0];
        #pragma unroll
        for (int w = 1; w < 4; ++w) {
            if (sd[w] > bestd || (sd[w] == bestd && sa[w] < besta)) {
                bestd = sd[w]; besta = sa[w];
            }
        }

        const int a = besta;

        // score at argmax, computed like jax.nn.softmax (subtract max, exp, norm)
        float l0 = c0[a];
        float l1 = c1[a];
        float m  = fmaxf(l0, l1);
        float e0 = expf(l0 - m);
        float e1 = expf(l1 - m);
        float s  = e1 / (e0 + e1);
        float lr = LR[0] * s;

        // gather the 4 loc deltas for (anchor a, batch b):
        // locs2[i][a][b] = locs_flat[b*12500 + i*3125 + a]
        const float* lb = locs + (size_t)b * (4 * NANCH);
        float t0 = lb[0 * NANCH + a];
        float t1 = lb[1 * NANCH + a];
        float t2 = lb[2 * NANCH + a];
        float t3 = lb[3 * NANCH + a];

        float ax = anchors[a * 4 + 0];
        float ay = anchors[a * 4 + 1];
        float aw = anchors[a * 4 + 2];
        float ah = anchors[a * 4 + 3];

        float dx = t0 * aw + ax;
        float dy = t1 * ah + ay;
        float dw = expf(t2) * aw;
        float dh = expf(t3) * ah;

        float bp0 = bboxs_prev[b * 4 + 0];
        float bp1 = bboxs_prev[b * 4 + 1];
        float bp2 = bboxs_prev[b * 4 + 2];
        float bp3 = bboxs_prev[b * 4 + 3];

        float width  = bp2 * (1.0f - lr) + dw * lr;
        float height = bp3 * (1.0f - lr) + dh * lr;
        float cx = bp0 + (bp2 - 1.0f) * 0.5f + dx;
        float cy = bp1 + (bp3 - 1.0f) * 0.5f + dy;

        // box_a = [cx - w/2, cy - h/2, w, h]; box_b = bboxs[b]
        float A0 = cx - width  * 0.5f;
        float A1 = cy - height * 0.5f;
        float A2 = width;
        float A3 = height;
        float B0 = bboxs[b * 4 + 0];
        float B1 = bboxs[b * 4 + 1];
        float B2 = bboxs[b * 4 + 2];
        float B3 = bboxs[b * 4 + 3];

        // _iou treats [.,2]/[.,3] as x2/y2 in the intersection AND area terms
        // (even though box_a holds w/h) -- replicate exactly.
        float xi = fmaxf(A0, B0);
        float yi = fmaxf(A1, B1);
        float wi = fmaxf(fminf(A2, B2) - xi, 0.0f);
        float hi = fmaxf(fminf(A3, B3) - yi, 0.0f);
        float area_i = wi * hi;
        float area_a = (A2 - A0) * (A3 - A1);
        float area_b = (B2 - B0) * (B3 - B1);
        float iou = area_i / fmaxf(area_a + area_b - area_i, 1e-5f);

        ws_iou[b] = iou;
    }
}

__global__ __launch_bounds__(256) void siam_finalize(
    const float* __restrict__ ws_iou, float* __restrict__ out)
{
    const int tid = threadIdx.x;
    float s = 0.0f;
    for (int i = tid; i < NB; i += 256) s += ws_iou[i];
    #pragma unroll
    for (int off = 32; off > 0; off >>= 1) s += __shfl_down(s, off, 64);

    __shared__ float sd[4];
    if ((tid & 63) == 0) sd[tid >> 6] = s;
    __syncthreads();
    if (tid == 0) {
        float t = sd[0] + sd[1] + sd[2] + sd[3];
        out[0] = 1.0f - t * (1.0f / 2048.0f);
    }
}

extern "C" void kernel_launch(void* const* d_in, const int* in_sizes, int n_in,
                              void* d_out, int out_size, void* d_ws, size_t ws_size,
                              hipStream_t stream) {
    const float* bboxs      = (const float*)d_in[0];
    const float* bboxs_prev = (const float*)d_in[1];
    const float* clss       = (const float*)d_in[2];
    const float* locs       = (const float*)d_in[3];
    const float* anchors    = (const float*)d_in[4];
    const float* LR         = (const float*)d_in[5];
    float*       out        = (float*)d_out;
    float*       ws         = (float*)d_ws;   // 2048 floats of per-batch IOU

    siam_argmax_iou<<<NB, 256, 0, stream>>>(bboxs, bboxs_prev, clss, locs,
                                            anchors, LR, ws);
    siam_finalize<<<1, 256, 0, stream>>>(ws, out);
}